// Round 8
// baseline (106.655 us; speedup 1.0000x reference)
//
#include <hip/hip_runtime.h>

// WaveKANLinear: out[n,o] = sum_d mexhat((ln(x)[n,d]-t[o,d])/s[o,d]) * ww[o,d]
//                           + silu(sum_d x[n,d]*bw[o,d])
// N=8192, D=128, O=128, float32.
// R13: R5/R7 post-mortem: pin vs remat is a wash (40.5 vs 42.0) -- the tax is
//      the PER-ROW weight re-access (2.1GB/dispatch ~52TB/s L2 demand in R5;
//      AGPR-move equivalent in R7), and '#pragma unroll 1' blocked the fix.
//      R13: no pin, 4-ROW BODY -- 16 weight float4 loaded once per body,
//      reused across 4 rows (weight traffic /4 -> ~21TB/s, under L2 ceiling;
//      or hoisted entirely if the allocator likes it -- either is fine).
//      4 independent exp chains + 4 independent 6-shuffle butterflies per
//      body give the cross-row ILP that 4 waves/SIMD couldn't supply.
//      Keep: dg=8x16d split, exact base reconstruction from ln (no raw-x
//      stream), conflict-free multicast layout (conflicts 32K in R7).
//      Floors: VALU ~14us, DS ~18us. Bench floor ~58us (unconditional ws
//      poison fill) -> prep + d_ws stay.

#define D_DIM 128
#define O_DIM 128
#define ROWS  32     // rows per block
#define BLOCK 1024   // 16 waves; o = wv*8 + (lane&7), dg = lane>>3 (16 d each)
#define XSTR  161    // f4 stride per dg block: 32 rows * 5 (4 f4 + 1 pad) + 1

#define C1     0.72134752f   // 0.5*log2(e); exp(-z^2/2) = exp2(-C1*z^2)
#define SQRT_C 0.84932180f   // sqrt(C1)
#define WWK    1.2023651f    // MEX_C / C1, MEX_C = 2/(sqrt(3)*pi^0.25)
#define LOG2E  1.44269504f

typedef float v2f __attribute__((ext_vector_type(2)));

// softplus(scale)+0.1 -> {t*is2, is2, ww*WWK, bw'}   (bw' = bw/gamma)
__device__ __forceinline__ void wk_pair(float sc, float tr, float w_w, float b_wp,
                                        float& wx, float& wy, float& wz, float& wb) {
    float sp  = fmaxf(sc, 0.0f) + __logf(1.0f + __expf(-fabsf(sc)));  // stable
    float is2 = SQRT_C / (sp + 0.1f);
    wx = tr * is2; wy = is2; wz = w_w * WWK; wb = b_wp;
}

// Prep: SoA d-pair layout. For d-pair p (d=2p,2p+1), column o:
//   ws[(p*O+o)*2+0] = {wx0,wx1,wy0,wy1}
//   ws[(p*O+o)*2+1] = {wz0,wz1,bw0/g0,bw1/g1}
__global__ __launch_bounds__(256) void wavekan_prep(
    const float* __restrict__ scale,
    const float* __restrict__ trans,
    const float* __restrict__ ww,
    const float* __restrict__ bw,
    const float* __restrict__ gamma,
    float4* __restrict__ wsW)
{
    int idx = blockIdx.x * blockDim.x + threadIdx.x;   // = o*64 + p
    if (idx >= O_DIM * (D_DIM / 2)) return;
    int o = idx >> 6;
    int p = idx & 63;
    int d0 = 2 * p;
    int i0 = o * D_DIM + d0;
    float wx0, wy0, wz0, wb0, wx1, wy1, wz1, wb1;
    wk_pair(scale[i0],     trans[i0],     ww[i0],     bw[i0]     / gamma[d0],     wx0, wy0, wz0, wb0);
    wk_pair(scale[i0 + 1], trans[i0 + 1], ww[i0 + 1], bw[i0 + 1] / gamma[d0 + 1], wx1, wy1, wz1, wb1);
    wsW[(p * O_DIM + o) * 2 + 0] = make_float4(wx0, wx1, wy0, wy1);
    wsW[(p * O_DIM + o) * 2 + 1] = make_float4(wz0, wz1, wb0, wb1);
}

template<bool USE_WS>
__global__ __launch_bounds__(BLOCK, 4) void wavekan_main(
    const float* __restrict__ x,
    const float* __restrict__ scale,
    const float* __restrict__ trans,
    const float* __restrict__ ww,
    const float* __restrict__ bw,
    const float* __restrict__ gamma,
    const float* __restrict__ beta,
    const float4* __restrict__ wsW,
    float* __restrict__ out,
    int N)
{
    // ln(x) staged once for 32 rows: [dg=8][row=32][4 f4 + 1 pad], +1 f4/dg.
    // Hot-loop reads: 8 distinct addrs/wave spanning all 32 banks ->
    // conflict-free 8-lane multicast.
    __shared__ float4 s_ln4[8 * XSTR];               // 20.6 KB
    __shared__ float2 s_stat[ROWS];                  // {mean, isr} per row

    const int tid  = threadIdx.x;
    const int lane = tid & 63;
    const int wv   = tid >> 6;                       // wave 0..15
    const int o    = wv * 8 + (lane & 7);            // output column
    const int dg   = lane >> 3;                      // d-group 0..7 (16 d each)
    const int row0 = blockIdx.x * ROWS;

    // Fallback weights (no-ws path only): computed once, kept in regs.
    float4 fA[8], fB[8];
    if (!USE_WS) {
        #pragma unroll
        for (int k = 0; k < 8; ++k) {
            const int d0 = dg * 16 + 2 * k;
            const int i0 = o * D_DIM + d0;
            float wx0, wy0, wz0, wb0, wx1, wy1, wz1, wb1;
            wk_pair(scale[i0],     trans[i0],     ww[i0],     bw[i0]     / gamma[d0],     wx0, wy0, wz0, wb0);
            wk_pair(scale[i0 + 1], trans[i0 + 1], ww[i0 + 1], bw[i0 + 1] / gamma[d0 + 1], wx1, wy1, wz1, wb1);
            fA[k] = make_float4(wx0, wx1, wy0, wy1);
            fB[k] = make_float4(wz0, wz1, wb0, wb1);
        }
    }

    // ---- Phase 1: LN of 32 rows. 32 lanes x 4 elems per row. ----
    {
        const int r    = tid >> 5;       // local row 0..31
        const int j    = tid & 31;       // lane within row group
        const int d0j  = j * 4;
        const int grow = row0 + r;

        float4 v4 = make_float4(0.f, 0.f, 0.f, 0.f);
        if (grow < N)
            v4 = *reinterpret_cast<const float4*>(x + (size_t)grow * D_DIM + d0j);

        float sum = (v4.x + v4.y) + (v4.z + v4.w);
        float ssq = (v4.x * v4.x + v4.y * v4.y) + (v4.z * v4.z + v4.w * v4.w);
        #pragma unroll
        for (int m = 1; m < 32; m <<= 1) {   // 32-lane butterfly (aligned groups)
            sum += __shfl_xor(sum, m, 64);
            ssq += __shfl_xor(ssq, m, 64);
        }
        const float mean = sum * (1.0f / D_DIM);
        const float var  = ssq * (1.0f / D_DIM) - mean * mean;
        const float rstd = rsqrtf(var + 1e-5f);

        float4 g4 = *reinterpret_cast<const float4*>(gamma + d0j);
        float4 b4 = *reinterpret_cast<const float4*>(beta + d0j);

        s_ln4[(j >> 2) * XSTR + r * 5 + (j & 3)] =
            make_float4((v4.x - mean) * rstd * g4.x + b4.x,
                        (v4.y - mean) * rstd * g4.y + b4.y,
                        (v4.z - mean) * rstd * g4.z + b4.z,
                        (v4.w - mean) * rstd * g4.w + b4.w);
        if (j == 0)
            s_stat[r] = make_float2(mean, sqrtf(var + 1e-5f));  // isr = 1/rstd
    }

    // ---- One-time per-o constants: cb = sum beta*bw', sb = sum bw ----
    float cb = 0.f, sb = 0.f;
    #pragma unroll
    for (int k = 0; k < 8; ++k) {
        float4 c = USE_WS ? wsW[((dg * 8 + k) * O_DIM + o) * 2 + 1] : fB[k];
        float2 bt = *reinterpret_cast<const float2*>(beta  + dg * 16 + 2 * k);
        float2 gt = *reinterpret_cast<const float2*>(gamma + dg * 16 + 2 * k);
        cb += bt.x * c.z + bt.y * c.w;
        sb += gt.x * c.z + gt.y * c.w;
    }
    cb += __shfl_xor(cb, 8, 64); cb += __shfl_xor(cb, 16, 64); cb += __shfl_xor(cb, 32, 64);
    sb += __shfl_xor(sb, 8, 64); sb += __shfl_xor(sb, 16, 64); sb += __shfl_xor(sb, 32, 64);

    __syncthreads();      // the only block-wide barrier

    // ---- Phase 2: 4-row bodies; weights loaded once per body ----
    for (int rb = 0; rb < ROWS; rb += 4) {
        // Weight set for this body: 16 f4, reused by 4 rows.
        float4 lA[8], lB[8];
        if (USE_WS) {
            #pragma unroll
            for (int k = 0; k < 8; ++k) {
                const int p = dg * 8 + k;
                lA[k] = wsW[(p * O_DIM + o) * 2 + 0];
                lB[k] = wsW[(p * O_DIM + o) * 2 + 1];
            }
        } else {
            #pragma unroll
            for (int k = 0; k < 8; ++k) { lA[k] = fA[k]; lB[k] = fB[k]; }
        }

        #pragma unroll
        for (int rr = 0; rr < 4; ++rr) {
            const int r  = rb + rr;
            const int xb = dg * XSTR + r * 5;
            v2f aw = {0.f, 0.f};
            v2f ab = {0.f, 0.f};
            #pragma unroll
            for (int k4 = 0; k4 < 4; ++k4) {
                float4 xl = s_ln4[xb + k4];        // 8-addr multicast, conflict-free
                float4 a0 = lA[2 * k4],     c0 = lB[2 * k4];
                float4 a1 = lA[2 * k4 + 1], c1 = lB[2 * k4 + 1];

                v2f u, qq, e;
                u  = (v2f){xl.x, xl.y} * (v2f){a0.z, a0.w} - (v2f){a0.x, a0.y};
                qq = u * u;
                e  = (v2f){__builtin_amdgcn_exp2f(-qq.x), __builtin_amdgcn_exp2f(-qq.y)};
                aw += ((qq - C1) * e) * (v2f){c0.x, c0.y};
                ab += (v2f){xl.x, xl.y} * (v2f){c0.z, c0.w};

                u  = (v2f){xl.z, xl.w} * (v2f){a1.z, a1.w} - (v2f){a1.x, a1.y};
                qq = u * u;
                e  = (v2f){__builtin_amdgcn_exp2f(-qq.x), __builtin_amdgcn_exp2f(-qq.y)};
                aw += ((qq - C1) * e) * (v2f){c1.x, c1.y};
                ab += (v2f){xl.z, xl.w} * (v2f){c1.z, c1.w};
            }
            float wav = aw.x + aw.y;
            float A   = ab.x + ab.y;
            // cross-dg reduce (dg = lane bits 3..5); 4 rows' chains overlap
            wav += __shfl_xor(wav, 8, 64); wav += __shfl_xor(wav, 16, 64); wav += __shfl_xor(wav, 32, 64);
            A   += __shfl_xor(A,   8, 64); A   += __shfl_xor(A,   16, 64); A   += __shfl_xor(A,   32, 64);

            if (dg == 0) {
                const int grow = row0 + r;
                if (grow < N) {
                    float2 st   = s_stat[r];                        // broadcast
                    float  base = (A - cb) * st.y + st.x * sb;      // exact reconstr.
                    float  sig  = 1.0f / (1.0f + __builtin_amdgcn_exp2f(-LOG2E * base));
                    out[(size_t)grow * O_DIM + o] = wav + base * sig;
                }
            }
        }
    }
}

extern "C" void kernel_launch(void* const* d_in, const int* in_sizes, int n_in,
                              void* d_out, int out_size, void* d_ws, size_t ws_size,
                              hipStream_t stream) {
    const float* x     = (const float*)d_in[0];
    const float* scale = (const float*)d_in[1];
    const float* trans = (const float*)d_in[2];
    const float* ww    = (const float*)d_in[3];
    const float* bw    = (const float*)d_in[4];
    const float* gamma = (const float*)d_in[5];
    const float* beta  = (const float*)d_in[6];
    float* out = (float*)d_out;

    const int N = in_sizes[0] / D_DIM;       // 8192
    const int grid = (N + ROWS - 1) / ROWS;  // 256 -> 1 block/CU

    const size_t ws_needed = (size_t)O_DIM * (D_DIM / 2) * 2 * sizeof(float4); // 256 KB
    if (ws_size >= ws_needed) {
        wavekan_prep<<<(O_DIM * (D_DIM / 2) + 255) / 256, 256, 0, stream>>>(
            scale, trans, ww, bw, gamma, (float4*)d_ws);
        wavekan_main<true><<<grid, BLOCK, 0, stream>>>(
            x, scale, trans, ww, bw, gamma, beta, (const float4*)d_ws, out, N);
    } else {
        wavekan_main<false><<<grid, BLOCK, 0, stream>>>(
            x, scale, trans, ww, bw, gamma, beta, nullptr, out, N);
    }
}